// Round 16
// baseline (120.770 us; speedup 1.0000x reference)
//
#include <hip/hip_runtime.h>
#include <math.h>

#define BB 8
#define CC 32
#define TT 9
#define LL 512
#define HH 8
#define DD 4
#define NBT (BB*TT)          // 72
#define RELN (2*LL-1)        // 1023
#define RLN2 1.4426950408889634f

typedef float  f4v __attribute__((ext_vector_type(4)));
typedef int    i4v __attribute__((ext_vector_type(4)));
typedef int    i2v __attribute__((ext_vector_type(2)));
typedef short  s8v __attribute__((ext_vector_type(8)));   // 8 bf16 = 4 VGPRs
typedef short  s4v __attribute__((ext_vector_type(4)));   // 4 bf16 = 2 VGPRs

#define EXP2(x) __builtin_amdgcn_exp2f(x)   // raw v_exp_f32 (exp2f -> OCML call)

// PV matmul: 16x16x16 bf16 MFMA via inline asm (instruction per cdna4_isa.md §10;
// builtin name on gfx950 is uncertain). acc: f4v (4 VGPR), a/b: s4v (2 VGPR).
// Back-to-back same-acc MFMA is the standard legal accumulate pattern.
#define MFMA16(acc, a, b) \
  asm("v_mfma_f32_16x16x16_bf16 %0, %1, %2, %0" : "+v"(acc) : "v"(a), "v"(b))

__device__ __forceinline__ unsigned cvtpk(float lo, float hi) {
  unsigned u;
  asm("v_cvt_pk_bf16_f32 %0, %1, %2" : "=v"(u) : "v"(lo), "v"(hi));
  return u;
}

// ---------------- prep: transpose pl_w (blocks 0..255) + mixed bias (blocks 256..259) ----
__global__ __launch_bounds__(256) void prep_kernel(
    const float* __restrict__ plw, float* __restrict__ plwT,
    const float* __restrict__ rpb, const float* __restrict__ Wl,
    float* __restrict__ mbr) {
  if (blockIdx.x < 256) {
    __shared__ float tile[32][33];
    int bx = (blockIdx.x & 15) * 32, by = (blockIdx.x >> 4) * 32;
    int tx = threadIdx.x & 31, ty = threadIdx.x >> 5;   // 32x8
    #pragma unroll
    for (int yy = ty; yy < 32; yy += 8)
      tile[yy][tx] = plw[(by + yy)*LL + bx + tx];
    __syncthreads();
    #pragma unroll
    for (int yy = ty; yy < 32; yy += 8)
      plwT[(bx + yy)*LL + by + tx] = tile[tx][yy];
  } else {
    int x = (blockIdx.x - 256) * 256 + threadIdx.x;
    if (x >= RELN) return;
    int idx = 1022 - x;
    float r[HH];
    #pragma unroll
    for (int h = 0; h < HH; ++h) r[h] = rpb[h*RELN + idx];
    #pragma unroll
    for (int Ho = 0; Ho < HH; ++Ho) {
      float acc = 0.f;
      #pragma unroll
      for (int h = 0; h < HH; ++h) acc += r[h] * Wl[h*HH + Ho];
      mbr[Ho*1024 + x] = RLN2 * acc;
    }
  }
}

// ---------------- q/k/v projection + l2norm (4-way co-split); V^T written directly ------
__global__ __launch_bounds__(256) void proj_kernel(
    const float* __restrict__ x,
    const float* __restrict__ Wq, const float* __restrict__ bq,
    const float* __restrict__ Wk, const float* __restrict__ bk,
    const float* __restrict__ Wv, const float* __restrict__ bv,
    float* __restrict__ qo, short* __restrict__ kbo, short* __restrict__ vt) {
  int gidx = blockIdx.x * 256 + threadIdx.x;    // 0..36863
  int l  = gidx & (LL-1);
  int bt = gidx >> 9;
  int b = bt / TT, t = bt - b*TT;
  const int hq = blockIdx.y * 2;

  float xv[CC];
  #pragma unroll
  for (int c = 0; c < CC; ++c)
    xv[c] = x[((b*CC + c)*TT + t)*LL + l];

  // Q (scaled by 0.5*log2e)
  #pragma unroll
  for (int h = hq; h < hq + 2; ++h) {
    float yv[DD];
    #pragma unroll
    for (int d = 0; d < DD; ++d) {
      int co = h*DD + d;
      float acc = bq[co];
      #pragma unroll
      for (int ci = 0; ci < CC; ++ci) acc += xv[ci] * Wq[co*CC + ci];
      yv[d] = acc;
    }
    float n = sqrtf(yv[0]*yv[0] + yv[1]*yv[1] + yv[2]*yv[2] + yv[3]*yv[3]);
    float inv = 0.5f * RLN2 / fmaxf(n, 1e-12f);
    *reinterpret_cast<float4*>(&qo[((size_t)bt*LL + l)*CC + h*DD]) =
        make_float4(yv[0]*inv, yv[1]*inv, yv[2]*inv, yv[3]*inv);
  }
  // K -> bf16 [bt][l][32]
  {
    unsigned ku[4];
    #pragma unroll
    for (int hh = 0; hh < 2; ++hh) {
      int h = hq + hh;
      float yv[DD];
      #pragma unroll
      for (int d = 0; d < DD; ++d) {
        int co = h*DD + d;
        float acc = bk[co];
        #pragma unroll
        for (int ci = 0; ci < CC; ++ci) acc += xv[ci] * Wk[co*CC + ci];
        yv[d] = acc;
      }
      float n = sqrtf(yv[0]*yv[0] + yv[1]*yv[1] + yv[2]*yv[2] + yv[3]*yv[3]);
      float inv = 1.0f / fmaxf(n, 1e-12f);
      ku[hh*2]   = cvtpk(yv[0]*inv, yv[1]*inv);
      ku[hh*2+1] = cvtpk(yv[2]*inv, yv[3]*inv);
    }
    *reinterpret_cast<uint4*>(kbo + ((size_t)bt*LL + l)*CC + hq*DD) =
        make_uint4(ku[0], ku[1], ku[2], ku[3]);
  }
  // V -> bf16 transposed: vt[bt][c][l]
  #pragma unroll
  for (int h = hq; h < hq + 2; ++h) {
    float yv[DD];
    #pragma unroll
    for (int d = 0; d < DD; ++d) {
      int co = h*DD + d;
      float acc = bv[co];
      #pragma unroll
      for (int ci = 0; ci < CC; ++ci) acc += xv[ci] * Wv[co*CC + ci];
      yv[d] = acc;
    }
    float n = sqrtf(yv[0]*yv[0] + yv[1]*yv[1] + yv[2]*yv[2] + yv[3]*yv[3]);
    float inv = 1.0f / fmaxf(n, 1e-12f);
    #pragma unroll
    for (int d = 0; d < DD; ++d) {
      unsigned u = cvtpk(yv[d]*inv, yv[d]*inv);
      int co = h*DD + d;
      reinterpret_cast<unsigned short*>(vt)[((size_t)bt*CC + co)*LL + l] =
          (unsigned short)(u & 0xffffu);
    }
  }
}

// ---------------- fused attention + Wm (v16: zero-shuffle PV via 16x16x16) ----------------
// 1152 blocks x 256 thr. Block = (bt, 32-row i-block). Wave w: i-tile = iblk*32+(w&1)*16,
// heads H=(w>>1)*4..+3. Per jp (32-j window) per head: 2 QK mfma 16x16x32 (A=K, B=QM,
// C=bias) -> exp2 -> cvt_pk. The packed pairs {uA0,uA1}/{uB0,uB1} ARE the 16x16x16
// B-fragment (k=(lane>>4)*4+e matches QK's row grouping 4g+r) -> 4 PV mfma 16x16x16
// (A=V^T), NO bpermutes. Output D[c][i]: i=col=c16 -> softmax inv is lane-local.
__global__ __launch_bounds__(256, 2) void attn_kernel(
    const float* __restrict__ q, const short* __restrict__ kb,
    const short* __restrict__ vt,
    const float* __restrict__ Wl, const float* __restrict__ Wc,
    const float* __restrict__ mbr,
    const float* __restrict__ Wm, const float* __restrict__ bm,
    float* __restrict__ out, float* __restrict__ xm8) {
  __shared__ float xch[2][64][9];   // H-hi partials, padded
  __shared__ float xt[32][33];      // x_att tile [i][c], padded
  __shared__ float sWm[32][33];     // Wm[co][ci], padded
  __shared__ float sbm[32];

  const int wgid = blockIdx.x;
  const int id   = (wgid & 7) * 144 + (wgid >> 3);   // 1152 % 8 == 0 -> bijective
  const int bt   = id >> 4;       // [0,72)
  const int iblk = id & 15;       // 32-row block
  const int b    = bt / TT, t = bt - b*TT;

  const int tid  = threadIdx.x;
  const int w    = __builtin_amdgcn_readfirstlane(tid >> 6);
  const int lane = tid & 63;
  const int g    = lane >> 4;     // 0..3
  const int c16  = lane & 15;
  const int it   = iblk*32 + (w & 1)*16;   // wave's i-tile base
  const int Hb   = (w >> 1)*4;

  // preload Wm/bm -> LDS (visible after first barrier)
  {
    int c4 = tid * 4;               // 0..1023
    int co = c4 >> 5, ci = c4 & 31;
    float4 wv = *reinterpret_cast<const float4*>(Wm + co*CC + ci);
    sWm[co][ci] = wv.x; sWm[co][ci+1] = wv.y; sWm[co][ci+2] = wv.z; sWm[co][ci+3] = wv.w;
    if (tid < 32) sbm[tid] = bm[tid];
  }

  // build 4 QM b-frags: B[k=c][n=i] = Wl[h(c)][H] * q[i][c]
  s8v bq4[4];
  {
    float qp[8];
    const float* qr = q + ((size_t)bt*LL + it + c16)*CC + g*8;
    float4 qa = *reinterpret_cast<const float4*>(qr);
    float4 qb = *reinterpret_cast<const float4*>(qr + 4);
    qp[0]=qa.x; qp[1]=qa.y; qp[2]=qa.z; qp[3]=qa.w;
    qp[4]=qb.x; qp[5]=qb.y; qp[6]=qb.z; qp[7]=qb.w;
    const int h0 = g*2;
    #pragma unroll
    for (int hh = 0; hh < 4; ++hh) {
      const int H = Hb + hh;
      const float wla = Wl[h0*HH + H];
      const float wlb = Wl[(h0+1)*HH + H];
      i4v uq;
      uq[0] = (int)cvtpk(qp[0]*wla, qp[1]*wla);
      uq[1] = (int)cvtpk(qp[2]*wla, qp[3]*wla);
      uq[2] = (int)cvtpk(qp[4]*wlb, qp[5]*wlb);
      uq[3] = (int)cvtpk(qp[6]*wlb, qp[7]*wlb);
      bq4[hh] = __builtin_bit_cast(s8v, uq);
    }
  }

  const short* kbase = kb + ((size_t)bt*LL)*CC + (size_t)c16*CC + g*8;
  const short* vb0 = vt + ((size_t)bt*CC)*LL + (size_t)c16*LL;        // c 0-15 rows
  const short* vb1 = vb0 + 16*LL;                                     // c 16-31 rows
  const float* mbase = mbr + Hb*1024 + 511 + 4*g - it - c16;

  f4v t0[4], t1[4];
  float den[4];
  #pragma unroll
  for (int hh = 0; hh < 4; ++hh) {
    t0[hh] = (f4v){0.f,0.f,0.f,0.f};
    t1[hh] = (f4v){0.f,0.f,0.f,0.f};
    den[hh] = 0.f;
  }

  #pragma unroll 1
  for (int jp = 0; jp < 16; ++jp) {
    const int j0 = jp*32;
    // K fragments (A of QK) and V^T fragments (A of PV, 16x16x16: k=4g+e)
    s8v ak0 = *reinterpret_cast<const s8v*>(kbase + (size_t)j0*CC);
    s8v ak1 = *reinterpret_cast<const s8v*>(kbase + (size_t)(j0+16)*CC);
    s4v va00 = *reinterpret_cast<const s4v*>(vb0 + j0 + 4*g);        // tile A, c-lo
    s4v va01 = *reinterpret_cast<const s4v*>(vb0 + j0 + 16 + 4*g);   // tile B, c-lo
    s4v va10 = *reinterpret_cast<const s4v*>(vb1 + j0 + 4*g);        // tile A, c-hi
    s4v va11 = *reinterpret_cast<const s4v*>(vb1 + j0 + 16 + 4*g);   // tile B, c-hi

    #pragma unroll
    for (int hh = 0; hh < 4; ++hh) {
      const float* m = mbase + hh*1024 + j0;
      unsigned uA0, uA1, uB0, uB1;
      {
        f4v cb = { m[0], m[1], m[2], m[3] };
        f4v d = __builtin_amdgcn_mfma_f32_16x16x32_bf16(ak0, bq4[hh], cb, 0, 0, 0);
        float e0 = EXP2(d[0]), e1 = EXP2(d[1]), e2 = EXP2(d[2]), e3 = EXP2(d[3]);
        uA0 = cvtpk(e0, e1); uA1 = cvtpk(e2, e3);
        den[hh] += (e0 + e1) + (e2 + e3);
      }
      {
        f4v cb = { m[16], m[17], m[18], m[19] };
        f4v d = __builtin_amdgcn_mfma_f32_16x16x32_bf16(ak1, bq4[hh], cb, 0, 0, 0);
        float e0 = EXP2(d[0]), e1 = EXP2(d[1]), e2 = EXP2(d[2]), e3 = EXP2(d[3]);
        uB0 = cvtpk(e0, e1); uB1 = cvtpk(e2, e3);
        den[hh] += (e0 + e1) + (e2 + e3);    // VALU between cvt_pk and MFMA (hazard gap)
      }
      s4v pA = __builtin_bit_cast(s4v, (i2v){(int)uA0, (int)uA1});
      s4v pB = __builtin_bit_cast(s4v, (i2v){(int)uB0, (int)uB1});
      MFMA16(t0[hh], va00, pA);
      MFMA16(t1[hh], va10, pA);
      MFMA16(t0[hh], va01, pB);
      MFMA16(t1[hh], va11, pB);
    }
  }

  // epilogue: denominators (lane-local for i=c16 after g-reduce); fold Wc/S scale.
  // t0[hh][r] = x_partial[c=4g+r][i=c16]; t1: c=16+4g+r. H' = c>>2 -> g (lo), 4+g (hi).
  f4v fin0 = {0.f,0.f,0.f,0.f}, fin1 = {0.f,0.f,0.f,0.f};
  #pragma unroll
  for (int hh = 0; hh < 4; ++hh) {
    const int H = Hb + hh;
    float dn = den[hh];
    dn += __shfl_xor(dn, 16);
    dn += __shfl_xor(dn, 32);
    float inv = __builtin_amdgcn_rcpf(dn);
    const float slo = inv * Wc[H*HH + g];
    const float shi = inv * Wc[H*HH + 4 + g];
    #pragma unroll
    for (int r = 0; r < 4; ++r) {
      fin0[r] += t0[hh][r] * slo;
      fin1[r] += t1[hh][r] * shi;
    }
  }

  // combine H-halves (waves 2,3 -> 0,1)
  if (w >= 2) {
    #pragma unroll
    for (int r = 0; r < 4; ++r) {
      xch[w-2][lane][r]     = fin0[r];
      xch[w-2][lane][4 + r] = fin1[r];
    }
  }
  __syncthreads();
  if (w < 2) {
    #pragma unroll
    for (int r = 0; r < 4; ++r) {
      float o0 = fin0[r] + xch[w][lane][r];
      float o1 = fin1[r] + xch[w][lane][4 + r];
      const int row = w*16 + c16;        // i_local
      xt[row][4*g + r]      = o0;
      xt[row][16 + 4*g + r] = o1;
    }
  }
  __syncthreads();

  // in-block Wm: 1024 outputs over 256 threads (4 co each, one row)
  {
    const int row = tid & 31;
    const int cos = (tid >> 5) * 4;
    float a0 = sbm[cos], a1 = sbm[cos+1], a2 = sbm[cos+2], a3 = sbm[cos+3];
    #pragma unroll
    for (int c = 0; c < CC; ++c) {
      float xv = xt[row][c];
      a0 += xv * sWm[cos][c];
      a1 += xv * sWm[cos+1][c];
      a2 += xv * sWm[cos+2][c];
      a3 += xv * sWm[cos+3][c];
    }
    const int l = iblk*32 + row;
    float av[4] = {a0, a1, a2, a3};
    #pragma unroll
    for (int u = 0; u < 4; ++u) {
      int co = cos + u;
      if (t < TT-1) out[((b*CC + co)*TT + t)*LL + l] = av[u];
      else          xm8[(b*CC + co)*LL + l] = av[u];
    }
  }
}

// ---------------- fused conv+BN+ReLU+token-linear+subtract (1024 thr, 2-way split) --------
__global__ __launch_bounds__(1024) void convpl_kernel(
    const float* __restrict__ out_in, const float* __restrict__ pp,
    const float* __restrict__ cw, const float* __restrict__ cb,
    const float* __restrict__ bng, const float* __restrict__ bnb,
    const float* __restrict__ plwT, const float* __restrict__ plb,
    const float* __restrict__ xm8, float* __restrict__ out) {
  __shared__ float sy[LL];
  __shared__ float part[2][LL];
  int bc = blockIdx.x;            // b*32 + co
  int b = bc >> 5, co = bc & 31;
  int tid = threadIdx.x;
  int l = tid & (LL-1);
  int h = tid >> 9;               // 0,1

  float acc = (h == 0) ? cb[co] : 0.f;
  #pragma unroll
  for (int cc = 0; cc < 16; ++cc) {
    int ci = h*16 + cc;
    const float* base = out_in + ((b*CC + ci)*TT)*LL + l;
    const float* wv = cw + (co*CC + ci)*TT;
    #pragma unroll
    for (int tq = 0; tq < TT-1; ++tq) acc += base[tq*LL] * wv[tq];
    acc += pp[ci*LL + l] * wv[TT-1];
  }
  part[h][l] = acc;
  __syncthreads();
  if (h == 0) {
    float scale = bng[co] * 0.999995000037499687f;   // 1/sqrt(1+1e-5)
    sy[l] = fmaxf((part[0][l] + part[1][l]) * scale + bnb[co], 0.f);
  }
  __syncthreads();
  float accp = (h == 0) ? plb[l] : 0.f;
  #pragma unroll 4
  for (int lq = 0; lq < 256; ++lq) {
    int ll = h*256 + lq;
    accp += sy[ll] * plwT[ll*LL + l];
  }
  part[h][l] = accp;
  __syncthreads();
  if (h == 0)
    out[((b*CC + co)*TT + (TT-1))*LL + l] = xm8[bc*LL + l] - (part[0][l] + part[1][l]);
}

extern "C" void kernel_launch(void* const* d_in, const int* in_sizes, int n_in,
                              void* d_out, int out_size, void* d_ws, size_t ws_size,
                              hipStream_t stream) {
  const float* x    = (const float*)d_in[0];
  const float* Wq   = (const float*)d_in[1];
  const float* bq   = (const float*)d_in[2];
  const float* Wk   = (const float*)d_in[3];
  const float* bk   = (const float*)d_in[4];
  const float* Wv   = (const float*)d_in[5];
  const float* bv   = (const float*)d_in[6];
  const float* Wm   = (const float*)d_in[7];
  const float* bm   = (const float*)d_in[8];
  const float* Wl   = (const float*)d_in[9];
  const float* Wc   = (const float*)d_in[10];
  const float* rpb  = (const float*)d_in[11];
  const float* pp   = (const float*)d_in[12];
  const float* cw   = (const float*)d_in[13];
  const float* cb   = (const float*)d_in[14];
  const float* bng  = (const float*)d_in[15];
  const float* bnb  = (const float*)d_in[16];
  const float* plw  = (const float*)d_in[17];
  const float* plb  = (const float*)d_in[18];
  float* out = (float*)d_out;

  float* ws = (float*)d_ws;
  const size_t NE = (size_t)NBT*LL*CC;         // 1179648
  float* q_ws   = ws;                          // NE fp32 [bt][l][32]
  short* kb_ws  = (short*)(q_ws + NE);         // NE bf16 [bt][l][32]
  short* vt_ws  = kb_ws + NE;                  // NE bf16 [bt][32][512]
  float* xm8    = (float*)(vt_ws + NE);        // 131072
  float* plwT   = xm8 + (size_t)BB*CC*LL;      // 262144
  float* mbias  = plwT + (size_t)LL*LL;        // 8*1024

  prep_kernel<<<260, 256, 0, stream>>>(plw, plwT, rpb, Wl, mbias);
  proj_kernel<<<dim3(144,4), 256, 0, stream>>>(x, Wq, bq, Wk, bk, Wv, bv,
                                               q_ws, kb_ws, vt_ws);
  attn_kernel<<<NBT*16, 256, 0, stream>>>(q_ws, kb_ws, vt_ws, Wl, Wc, mbias,
                                          Wm, bm, out, xm8);
  convpl_kernel<<<BB*CC, 1024, 0, stream>>>(out, pp, cw, cb, bng, bnb,
                                            plwT, plb, xm8, out);
}